// Round 6
// baseline (205.579 us; speedup 1.0000x reference)
//
#include <hip/hip_runtime.h>

typedef _Float16 f16x8 __attribute__((ext_vector_type(8)));
typedef _Float16 f16x4 __attribute__((ext_vector_type(4)));
typedef _Float16 f16x2 __attribute__((ext_vector_type(2)));
typedef __fp16 hf16x2 __attribute__((ext_vector_type(2)));
typedef float f32x4 __attribute__((ext_vector_type(4)));

__device__ __forceinline__ float fast_exp2(float x) {
#if __has_builtin(__builtin_amdgcn_exp2f)
  return __builtin_amdgcn_exp2f(x);
#else
  return exp2f(x);
#endif
}

__device__ __forceinline__ f16x2 pk_cvt(float a, float b) {
#if __has_builtin(__builtin_amdgcn_cvt_pkrtz)
  union { hf16x2 h; f16x2 f; } u;
  u.h = __builtin_amdgcn_cvt_pkrtz(a, b);
  return u.f;
#else
  f16x2 r; r[0] = (_Float16)a; r[1] = (_Float16)b; return r;
#endif
}

// v_permlane32_swap_b32: x <- {x.lanes[0:31], y.lanes[0:31]},
//                        y <- {x.lanes[32:63], y.lanes[32:63]}
__device__ __forceinline__ void qswap32(int& x, int& y) {
  asm("v_permlane32_swap_b32 %0, %1" : "+v"(x), "+v"(y));
}

// key-index involution: swap bits 2 and 3 (sigma == pi, self-inverse)
__device__ __forceinline__ int swz23(int c) {
  return (c & ~12) | ((c & 4) << 1) | ((c & 8) >> 1);
}

// ---------------- fused f32 -> f16 convert prepass ----------------
__global__ void cvt_all(const float* __restrict__ x,
                        const float* __restrict__ Wq, const float* __restrict__ Wk,
                        const float* __restrict__ Wv, const float* __restrict__ Wo,
                        _Float16* __restrict__ xf, _Float16* __restrict__ wf) {
  int g = blockIdx.x * blockDim.x + threadIdx.x;
  const float* src;
  _Float16* dst;
  if (g < 524288) {
    src = x + (size_t)g * 8;
    dst = xf + (size_t)g * 8;
  } else {
    int g2 = g - 524288;
    int z = g2 >> 15, off = g2 & 32767;
    const float* W = (z == 0) ? Wq : (z == 1) ? Wk : (z == 2) ? Wv : Wo;
    src = W + (size_t)off * 8;
    dst = wf + (size_t)z * 262144 + (size_t)off * 8;
  }
  f32x4 a = *(const f32x4*)src;
  f32x4 b = *(const f32x4*)(src + 4);
  f16x8 o;
  o[0] = (_Float16)a[0]; o[1] = (_Float16)a[1];
  o[2] = (_Float16)a[2]; o[3] = (_Float16)a[3];
  o[4] = (_Float16)b[0]; o[5] = (_Float16)b[1];
  o[6] = (_Float16)b[2]; o[7] = (_Float16)b[3];
  *(f16x8*)dst = o;
}

// ---------------- fused QKV projection: y = x @ W^T + b ----------------
// Q,K (z=0,1): SWAPPED-operand MFMA puts feature index in the row slot
// (quad*4+r) and token in col -> epilogue emits f16x4 stores of 4 consecutive
// d per token (16 stores/thread vs 64 scalar). V (z=2): original order,
// written TRANSPOSED [bh][d][t] with f16x4 along t.
__global__ __launch_bounds__(256, 2)
void qkv_gemm(const _Float16* __restrict__ X, const _Float16* __restrict__ Wf,
              const float* __restrict__ bq, const float* __restrict__ bk,
              const float* __restrict__ bv, _Float16* __restrict__ dst3) {
  __shared__ __align__(16) _Float16 As[128][72];
  __shared__ __align__(16) _Float16 Bs[128][72];
  const int z = blockIdx.z;
  const _Float16* Wz = Wf + (size_t)z * 262144;
  const float* bias = (z == 0) ? bq : (z == 1 ? bk : bv);
  _Float16* dst = dst3 + (size_t)z * 4194304;
  const float scale = (z == 0) ? 0.18033688011112042f : 1.0f;

  const int t = threadIdx.x;
  const int lane = t & 63, wave = t >> 6;
  const int quad = lane >> 4, col = lane & 15;
  const int wm = (wave & 1) * 64, wn = (wave >> 1) * 64;
  const int m0 = blockIdx.x * 128, n0 = blockIdx.y * 128;

  f32x4 acc[4][4] = {};

  for (int k0 = 0; k0 < 512; k0 += 64) {
    __syncthreads();
#pragma unroll
    for (int i = 0; i < 4; i++) {
      int flat = i * 2048 + t * 8;
      int r = flat >> 6, c = flat & 63;
      *(f16x8*)&As[r][c] = *(const f16x8*)&X[(size_t)(m0 + r) * 512 + k0 + c];
      *(f16x8*)&Bs[r][c] = *(const f16x8*)&Wz[(size_t)(n0 + r) * 512 + k0 + c];
    }
    __syncthreads();
#pragma unroll
    for (int ks = 0; ks < 2; ks++) {
      f16x8 a[4], b[4];
#pragma unroll
      for (int i = 0; i < 4; i++) {
        a[i] = *(const f16x8*)&As[wm + i * 16 + col][ks * 32 + quad * 8];
        b[i] = *(const f16x8*)&Bs[wn + i * 16 + col][ks * 32 + quad * 8];
      }
      if (z != 2) {
        // swapped: D row (quad*4+r) <- W row (feature n), col <- X row (token)
#pragma unroll
        for (int mi = 0; mi < 4; mi++)
#pragma unroll
          for (int ni = 0; ni < 4; ni++)
            acc[mi][ni] = __builtin_amdgcn_mfma_f32_16x16x32_f16(b[ni], a[mi], acc[mi][ni], 0, 0, 0);
      } else {
#pragma unroll
        for (int mi = 0; mi < 4; mi++)
#pragma unroll
          for (int ni = 0; ni < 4; ni++)
            acc[mi][ni] = __builtin_amdgcn_mfma_f32_16x16x32_f16(a[mi], b[ni], acc[mi][ni], 0, 0, 0);
      }
    }
  }

  if (z != 2) {
    // Q,K: [bh][t][d], f16x4 of 4 consecutive d per token
#pragma unroll
    for (int ni = 0; ni < 4; ni++) {
      int nb = n0 + wn + ni * 16 + quad * 4;   // 4 consecutive features
      int h = nb >> 6, d0 = nb & 63;
      f32x4 bb = *(const f32x4*)&bias[nb];
#pragma unroll
      for (int mi = 0; mi < 4; mi++) {
        int m = m0 + wm + mi * 16 + col;
        int b = m >> 12, tt = m & 4095;
        f16x4 ov;
#pragma unroll
        for (int r = 0; r < 4; r++)
          ov[r] = (_Float16)((acc[mi][ni][r] + bb[r]) * scale);
        *(f16x4*)&dst[((size_t)(b * 8 + h) * 4096 + tt) * 64 + d0] = ov;
      }
    }
  } else {
    // V: [bh][d][t] layout, vectorized f16x4 along t
#pragma unroll
    for (int ni = 0; ni < 4; ni++) {
      int n = n0 + wn + ni * 16 + col;
      float bv_ = bias[n];
      int h = n >> 6, d = n & 63;
#pragma unroll
      for (int mi = 0; mi < 4; mi++) {
        int m = m0 + wm + mi * 16 + quad * 4;
        int b = m >> 12, tt = m & 4095;
        f16x4 ov;
#pragma unroll
        for (int r = 0; r < 4; r++) ov[r] = (_Float16)(acc[mi][ni][r] + bv_);
        *(f16x4*)&dst[((size_t)((b * 8 + h) * 64 + d)) * 4096 + tt] = ov;
      }
    }
  }
}

// ---------------- flash attention, one (b,h) x 128-query tile per block -----
// R4-verified kernel + XCD-aware block swizzle: all 32 q-tiles of one (b,h)
// land on one XCD (2 bh per XCD, KV working set 4MB ~= L2), cutting K/V
// re-fetch across XCD L2s. PV at K=32 via permlane32_swap + bit2<->3 V
// swizzle; lsum on VALU; setprio around MFMA clusters.
__global__ __launch_bounds__(256, 2)
void attn_kernel(const _Float16* __restrict__ Q, const _Float16* __restrict__ K,
                 const _Float16* __restrict__ V, _Float16* __restrict__ O) {
  __shared__ __align__(16) _Float16 Ks[2][128][72];
  __shared__ __align__(16) _Float16 Vt[2][64][136]; // pitch 136: 16B-aligned rows

  const int t = threadIdx.x;
  const int lane = t & 63, wave = t >> 6;
  const int quad = lane >> 4, col = lane & 15;
  // XCD swizzle: id%8 = XCD (round-robin dispatch); give each XCD 2 whole bh
  const int id = blockIdx.y * 32 + blockIdx.x;
  const int xcd = id & 7, slot = id >> 3;
  const int bh = xcd * 2 + (slot >> 5);
  const int q0 = (slot & 31) * 128;
  const _Float16* Qb = Q + (size_t)bh * 4096 * 64;
  const _Float16* Kbh = K + (size_t)bh * 4096 * 64;
  const _Float16* Vg = V + (size_t)bh * 64 * 4096;   // [d][t]

  // staging coords
  const int sr = (t * 8) >> 6, sc = (t * 8) & 63;    // K rows: r = sr + 32*i
  const int vrow = t >> 4, vcol = (t & 15) * 8;      // V^T rows: d = vrow + 16*it
  const int vc0 = swz23(vcol);                       // sigma(vcol)
  const int vc1 = swz23(vcol + 4);                   // sigma(vcol+4)

  // Q as B-fragment: B[n=query=mt*16+col][k=d=ks*32+quad*8+j]
  f16x8 qf[2][2];
#pragma unroll
  for (int mt = 0; mt < 2; mt++)
#pragma unroll
    for (int ks = 0; ks < 2; ks++)
      qf[mt][ks] = *(const f16x8*)&Qb[(size_t)(q0 + wave * 32 + mt * 16 + col) * 64 +
                                      ks * 32 + quad * 8];

  const f32x4 fz = {0.f, 0.f, 0.f, 0.f};

  f16x8 kreg[4], vreg[4];
  // prologue: load tile 0
#pragma unroll
  for (int i = 0; i < 4; i++)
    kreg[i] = *(const f16x8*)&Kbh[(size_t)(sr + 32 * i) * 64 + sc];
#pragma unroll
  for (int it = 0; it < 4; it++)
    vreg[it] = *(const f16x8*)&Vg[(size_t)(it * 16 + vrow) * 4096 + vcol];
#pragma unroll
  for (int i = 0; i < 4; i++)
    *(f16x8*)&Ks[0][sr + 32 * i][sc] = kreg[i];
#pragma unroll
  for (int it = 0; it < 4; it++) {
    f16x4 lo, hi;
#pragma unroll
    for (int u = 0; u < 4; u++) { lo[u] = vreg[it][u]; hi[u] = vreg[it][u + 4]; }
    *(f16x4*)&Vt[0][it * 16 + vrow][vc0] = lo;
    *(f16x4*)&Vt[0][it * 16 + vrow][vc1] = hi;
  }
  __syncthreads();

  // o_acc[mt][dt][r] = O^T[d=dt*16+quad*4+r][query=mt*16+col]
  f32x4 o_acc[2][4] = {};
  // per-lane partial row-sum of P for query=col, keys {nt*16+quad*4+r, all nt,j}
  float lsum[2] = {0.f, 0.f};

  for (int j = 0; j < 32; j++) {
    const int buf = j & 1;
    // prefetch tile j+1 into registers (latency hidden behind compute)
    if (j + 1 < 32) {
      const _Float16* Kb = Kbh + (size_t)(j + 1) * 128 * 64;
#pragma unroll
      for (int i = 0; i < 4; i++)
        kreg[i] = *(const f16x8*)&Kb[(size_t)(sr + 32 * i) * 64 + sc];
#pragma unroll
      for (int it = 0; it < 4; it++)
        vreg[it] = *(const f16x8*)&Vg[(size_t)(it * 16 + vrow) * 4096 +
                                      (j + 1) * 128 + vcol];
    }

    // S^T[key][query]: s[mt][nt][r] = S[q=mt*16+col][key=nt*16+quad*4+r]
    f32x4 s[2][8];
    __builtin_amdgcn_s_setprio(1);
#pragma unroll
    for (int nt = 0; nt < 8; nt++) {
      f16x8 kf = *(const f16x8*)&Ks[buf][nt * 16 + col][quad * 8];
#pragma unroll
      for (int mt = 0; mt < 2; mt++)
        s[mt][nt] = __builtin_amdgcn_mfma_f32_16x16x32_f16(kf, qf[mt][0], fz, 0, 0, 0);
    }
#pragma unroll
    for (int nt = 0; nt < 8; nt++) {
      f16x8 kf = *(const f16x8*)&Ks[buf][nt * 16 + col][32 + quad * 8];
#pragma unroll
      for (int mt = 0; mt < 2; mt++)
        s[mt][nt] = __builtin_amdgcn_mfma_f32_16x16x32_f16(kf, qf[mt][1], s[mt][nt], 0, 0, 0);
    }
    __builtin_amdgcn_s_setprio(0);

    // P = exp2(S^T): bare v_exp_f32 + packed f32->f16; l-accum on VALU pipe
    f16x4 pf[2][8];
#pragma unroll
    for (int mt = 0; mt < 2; mt++) {
#pragma unroll
      for (int nt = 0; nt < 8; nt++) {
        float p0 = fast_exp2(s[mt][nt][0]);
        float p1 = fast_exp2(s[mt][nt][1]);
        float p2 = fast_exp2(s[mt][nt][2]);
        float p3 = fast_exp2(s[mt][nt][3]);
        lsum[mt] += (p0 + p1) + (p2 + p3);
        union { f16x4 v4; f16x2 v2[2]; } u;
        u.v2[0] = pk_cvt(p0, p1);
        u.v2[1] = pk_cvt(p2, p3);
        pf[mt][nt] = u.v4;
      }
    }

    // O^T += V^T P^T at K=32: build 8-keys/lane P fragments via permlane32_swap
    __builtin_amdgcn_s_setprio(1);
#pragma unroll
    for (int u = 0; u < 4; u++) {
      f16x8 p8[2];
#pragma unroll
      for (int mt = 0; mt < 2; mt++) {
        union { f16x4 v; int d[2]; } X, Y;
        X.v = pf[mt][2 * u]; Y.v = pf[mt][2 * u + 1];
        int x0 = X.d[0], y0 = Y.d[0], x1 = X.d[1], y1 = Y.d[1];
        qswap32(x0, y0);   // x0 = low halves (j0,1), y0 = high halves (j4,5)
        qswap32(x1, y1);   // x1 = (j2,3),           y1 = (j6,7)
        union { int d[4]; f16x8 v; } P;
        P.d[0] = x0; P.d[1] = x1; P.d[2] = y0; P.d[3] = y1;
        p8[mt] = P.v;
      }
#pragma unroll
      for (int dt = 0; dt < 4; dt++) {
        f16x8 vf = *(const f16x8*)&Vt[buf][dt * 16 + col][u * 32 + quad * 8];
#pragma unroll
        for (int mt = 0; mt < 2; mt++)
          o_acc[mt][dt] = __builtin_amdgcn_mfma_f32_16x16x32_f16(vf, p8[mt], o_acc[mt][dt], 0, 0, 0);
      }
    }
    __builtin_amdgcn_s_setprio(0);

    // write prefetched tile into the other buffer; single barrier per iter
    if (j + 1 < 32) {
      const int nb = buf ^ 1;
#pragma unroll
      for (int i = 0; i < 4; i++)
        *(f16x8*)&Ks[nb][sr + 32 * i][sc] = kreg[i];
#pragma unroll
      for (int it = 0; it < 4; it++) {
        f16x4 lo, hi;
#pragma unroll
        for (int u = 0; u < 4; u++) { lo[u] = vreg[it][u]; hi[u] = vreg[it][u + 4]; }
        *(f16x4*)&Vt[nb][it * 16 + vrow][vc0] = lo;
        *(f16x4*)&Vt[nb][it * 16 + vrow][vc1] = hi;
      }
      __syncthreads();
    }
  }

  // epilogue: complete l across quads (lanes col, col+16, col+32, col+48),
  // then O /= l, write [b][t][h*64+d] fp16 (row-major 8192x512)
  const int b = bh >> 3, h = bh & 7;
#pragma unroll
  for (int mt = 0; mt < 2; mt++) {
    float l = lsum[mt];
    l += __shfl_xor(l, 16, 64);
    l += __shfl_xor(l, 32, 64);
    int row = q0 + wave * 32 + mt * 16 + col;
    float inv = 1.0f / l;
#pragma unroll
    for (int dt = 0; dt < 4; dt++) {
      f16x4 ov;
#pragma unroll
      for (int r = 0; r < 4; r++) ov[r] = (_Float16)(o_acc[mt][dt][r] * inv);
      *(f16x4*)&O[((size_t)(b * 4096 + row)) * 512 + h * 64 + dt * 16 + quad * 4] = ov;
    }
  }
}

// ---------------- output projection: out = ao @ Wo^T + bo -> fp32 ----------
__global__ __launch_bounds__(256, 2)
void out_gemm(const _Float16* __restrict__ X, const _Float16* __restrict__ Wo,
              const float* __restrict__ bias, float* __restrict__ out) {
  __shared__ __align__(16) _Float16 As[128][72];
  __shared__ __align__(16) _Float16 Bs[128][72];
  const int t = threadIdx.x;
  const int lane = t & 63, wave = t >> 6;
  const int quad = lane >> 4, col = lane & 15;
  const int wm = (wave & 1) * 64, wn = (wave >> 1) * 64;
  const int m0 = blockIdx.x * 128, n0 = blockIdx.y * 128;

  f32x4 acc[4][4] = {};

  for (int k0 = 0; k0 < 512; k0 += 64) {
    __syncthreads();
#pragma unroll
    for (int i = 0; i < 4; i++) {
      int flat = i * 2048 + t * 8;
      int r = flat >> 6, c = flat & 63;
      *(f16x8*)&As[r][c] = *(const f16x8*)&X[(size_t)(m0 + r) * 512 + k0 + c];
      *(f16x8*)&Bs[r][c] = *(const f16x8*)&Wo[(size_t)(n0 + r) * 512 + k0 + c];
    }
    __syncthreads();
#pragma unroll
    for (int ks = 0; ks < 2; ks++) {
      f16x8 a[4], b[4];
#pragma unroll
      for (int i = 0; i < 4; i++) {
        a[i] = *(const f16x8*)&As[wm + i * 16 + col][ks * 32 + quad * 8];
        b[i] = *(const f16x8*)&Bs[wn + i * 16 + col][ks * 32 + quad * 8];
      }
#pragma unroll
      for (int mi = 0; mi < 4; mi++)
#pragma unroll
        for (int ni = 0; ni < 4; ni++)
          acc[mi][ni] = __builtin_amdgcn_mfma_f32_16x16x32_f16(a[mi], b[ni], acc[mi][ni], 0, 0, 0);
    }
  }

#pragma unroll
  for (int ni = 0; ni < 4; ni++) {
    int n = n0 + wn + ni * 16 + col;
    float bv_ = bias[n];
#pragma unroll
    for (int mi = 0; mi < 4; mi++) {
#pragma unroll
      for (int r = 0; r < 4; r++) {
        int m = m0 + wm + mi * 16 + quad * 4 + r;
        out[(size_t)m * 512 + n] = acc[mi][ni][r] + bv_;
      }
    }
  }
}

extern "C" void kernel_launch(void* const* d_in, const int* in_sizes, int n_in,
                              void* d_out, int out_size, void* d_ws, size_t ws_size,
                              hipStream_t stream) {
  const float* x  = (const float*)d_in[0];
  const float* Wq = (const float*)d_in[1];
  const float* bq = (const float*)d_in[2];
  const float* Wk = (const float*)d_in[3];
  const float* bk = (const float*)d_in[4];
  const float* Wv = (const float*)d_in[5];
  const float* bv = (const float*)d_in[6];
  const float* Wo = (const float*)d_in[7];
  const float* bo = (const float*)d_in[8];

  char* ws = (char*)d_ws;
  _Float16* xf  = (_Float16*)(ws);                 //  8 MiB: x as f16 (dead after qkv)
  _Float16* wf  = (_Float16*)(ws + (8u << 20));    //  2 MiB: Wq,Wk,Wv,Wo f16
  _Float16* qkv = (_Float16*)(ws + (10u << 20));   // 24 MiB: Q,K [bh][t][d]; V [bh][d][t]
  _Float16* ao  = (_Float16*)(ws);                 //  8 MiB: attn out (reuses xf)

  cvt_all<<<2560, 256, 0, stream>>>(x, Wq, Wk, Wv, Wo, xf, wf);

  qkv_gemm<<<dim3(64, 4, 3), 256, 0, stream>>>(xf, wf, bq, bk, bv, qkv);

  attn_kernel<<<dim3(32, 16), 256, 0, stream>>>(qkv, qkv + 4194304,
                                                qkv + 2 * 4194304, ao);

  out_gemm<<<dim3(64, 4), 256, 0, stream>>>(ao, wf + 3 * 262144, bo,
                                            (float*)d_out);
}

// Round 7
// 199.528 us; speedup vs baseline: 1.0303x; 1.0303x over previous
//
#include <hip/hip_runtime.h>

typedef _Float16 f16x8 __attribute__((ext_vector_type(8)));
typedef _Float16 f16x4 __attribute__((ext_vector_type(4)));
typedef _Float16 f16x2 __attribute__((ext_vector_type(2)));
typedef __fp16 hf16x2 __attribute__((ext_vector_type(2)));
typedef float f32x4 __attribute__((ext_vector_type(4)));

__device__ __forceinline__ float fast_exp2(float x) {
#if __has_builtin(__builtin_amdgcn_exp2f)
  return __builtin_amdgcn_exp2f(x);
#else
  return exp2f(x);
#endif
}

__device__ __forceinline__ f16x2 pk_cvt(float a, float b) {
#if __has_builtin(__builtin_amdgcn_cvt_pkrtz)
  union { hf16x2 h; f16x2 f; } u;
  u.h = __builtin_amdgcn_cvt_pkrtz(a, b);
  return u.f;
#else
  f16x2 r; r[0] = (_Float16)a; r[1] = (_Float16)b; return r;
#endif
}

// v_permlane32_swap_b32: x <- {x.lanes[0:31], y.lanes[0:31]},
//                        y <- {x.lanes[32:63], y.lanes[32:63]}
__device__ __forceinline__ void qswap32(int& x, int& y) {
  asm("v_permlane32_swap_b32 %0, %1" : "+v"(x), "+v"(y));
}

// key-index involution: swap bits 2 and 3 (sigma == pi, self-inverse)
__device__ __forceinline__ int swz23(int c) {
  return (c & ~12) | ((c & 4) << 1) | ((c & 8) >> 1);
}

// ---------------- fused f32 -> f16 convert prepass ----------------
__global__ void cvt_all(const float* __restrict__ x,
                        const float* __restrict__ Wq, const float* __restrict__ Wk,
                        const float* __restrict__ Wv, const float* __restrict__ Wo,
                        _Float16* __restrict__ xf, _Float16* __restrict__ wf) {
  int g = blockIdx.x * blockDim.x + threadIdx.x;
  const float* src;
  _Float16* dst;
  if (g < 524288) {
    src = x + (size_t)g * 8;
    dst = xf + (size_t)g * 8;
  } else {
    int g2 = g - 524288;
    int z = g2 >> 15, off = g2 & 32767;
    const float* W = (z == 0) ? Wq : (z == 1) ? Wk : (z == 2) ? Wv : Wo;
    src = W + (size_t)off * 8;
    dst = wf + (size_t)z * 262144 + (size_t)off * 8;
  }
  f32x4 a = *(const f32x4*)src;
  f32x4 b = *(const f32x4*)(src + 4);
  f16x8 o;
  o[0] = (_Float16)a[0]; o[1] = (_Float16)a[1];
  o[2] = (_Float16)a[2]; o[3] = (_Float16)a[3];
  o[4] = (_Float16)b[0]; o[5] = (_Float16)b[1];
  o[6] = (_Float16)b[2]; o[7] = (_Float16)b[3];
  *(f16x8*)dst = o;
}

// ---------------- fused QKV projection: y = x @ W^T + b ----------------
// Q,K (z=0,1): SWAPPED-operand MFMA (feature in row slot, token in col) ->
// f16x4 stores of 4 consecutive d per token. Branch hoisted OUT of the K-loop
// (two specialized loops) so the mainloop has a single MFMA sequence.
// V (z=2): original order, written TRANSPOSED [bh][d][t].
__global__ __launch_bounds__(256, 2)
void qkv_gemm(const _Float16* __restrict__ X, const _Float16* __restrict__ Wf,
              const float* __restrict__ bq, const float* __restrict__ bk,
              const float* __restrict__ bv, _Float16* __restrict__ dst3) {
  __shared__ __align__(16) _Float16 As[128][72];
  __shared__ __align__(16) _Float16 Bs[128][72];
  const int z = blockIdx.z;
  const _Float16* Wz = Wf + (size_t)z * 262144;
  const float* bias = (z == 0) ? bq : (z == 1 ? bk : bv);
  _Float16* dst = dst3 + (size_t)z * 4194304;
  const float scale = (z == 0) ? 0.18033688011112042f : 1.0f;

  const int t = threadIdx.x;
  const int lane = t & 63, wave = t >> 6;
  const int quad = lane >> 4, col = lane & 15;
  const int wm = (wave & 1) * 64, wn = (wave >> 1) * 64;
  const int m0 = blockIdx.x * 128, n0 = blockIdx.y * 128;

  f32x4 acc[4][4] = {};

  if (z != 2) {
    for (int k0 = 0; k0 < 512; k0 += 64) {
      __syncthreads();
#pragma unroll
      for (int i = 0; i < 4; i++) {
        int flat = i * 2048 + t * 8;
        int r = flat >> 6, c = flat & 63;
        *(f16x8*)&As[r][c] = *(const f16x8*)&X[(size_t)(m0 + r) * 512 + k0 + c];
        *(f16x8*)&Bs[r][c] = *(const f16x8*)&Wz[(size_t)(n0 + r) * 512 + k0 + c];
      }
      __syncthreads();
#pragma unroll
      for (int ks = 0; ks < 2; ks++) {
        f16x8 a[4], b[4];
#pragma unroll
        for (int i = 0; i < 4; i++) {
          a[i] = *(const f16x8*)&As[wm + i * 16 + col][ks * 32 + quad * 8];
          b[i] = *(const f16x8*)&Bs[wn + i * 16 + col][ks * 32 + quad * 8];
        }
#pragma unroll
        for (int mi = 0; mi < 4; mi++)
#pragma unroll
          for (int ni = 0; ni < 4; ni++)
            acc[mi][ni] = __builtin_amdgcn_mfma_f32_16x16x32_f16(b[ni], a[mi], acc[mi][ni], 0, 0, 0);
      }
    }
    // Q,K: [bh][t][d], f16x4 of 4 consecutive d per token
#pragma unroll
    for (int ni = 0; ni < 4; ni++) {
      int nb = n0 + wn + ni * 16 + quad * 4;   // 4 consecutive features
      int h = nb >> 6, d0 = nb & 63;
      f32x4 bb = *(const f32x4*)&bias[nb];
#pragma unroll
      for (int mi = 0; mi < 4; mi++) {
        int m = m0 + wm + mi * 16 + col;
        int b = m >> 12, tt = m & 4095;
        f16x4 ov;
#pragma unroll
        for (int r = 0; r < 4; r++)
          ov[r] = (_Float16)((acc[mi][ni][r] + bb[r]) * scale);
        *(f16x4*)&dst[((size_t)(b * 8 + h) * 4096 + tt) * 64 + d0] = ov;
      }
    }
  } else {
    for (int k0 = 0; k0 < 512; k0 += 64) {
      __syncthreads();
#pragma unroll
      for (int i = 0; i < 4; i++) {
        int flat = i * 2048 + t * 8;
        int r = flat >> 6, c = flat & 63;
        *(f16x8*)&As[r][c] = *(const f16x8*)&X[(size_t)(m0 + r) * 512 + k0 + c];
        *(f16x8*)&Bs[r][c] = *(const f16x8*)&Wz[(size_t)(n0 + r) * 512 + k0 + c];
      }
      __syncthreads();
#pragma unroll
      for (int ks = 0; ks < 2; ks++) {
        f16x8 a[4], b[4];
#pragma unroll
        for (int i = 0; i < 4; i++) {
          a[i] = *(const f16x8*)&As[wm + i * 16 + col][ks * 32 + quad * 8];
          b[i] = *(const f16x8*)&Bs[wn + i * 16 + col][ks * 32 + quad * 8];
        }
#pragma unroll
        for (int mi = 0; mi < 4; mi++)
#pragma unroll
          for (int ni = 0; ni < 4; ni++)
            acc[mi][ni] = __builtin_amdgcn_mfma_f32_16x16x32_f16(a[mi], b[ni], acc[mi][ni], 0, 0, 0);
      }
    }
    // V: [bh][d][t] layout, vectorized f16x4 along t
#pragma unroll
    for (int ni = 0; ni < 4; ni++) {
      int n = n0 + wn + ni * 16 + col;
      float bv_ = bias[n];
      int h = n >> 6, d = n & 63;
#pragma unroll
      for (int mi = 0; mi < 4; mi++) {
        int m = m0 + wm + mi * 16 + quad * 4;
        int b = m >> 12, tt = m & 4095;
        f16x4 ov;
#pragma unroll
        for (int r = 0; r < 4; r++) ov[r] = (_Float16)(acc[mi][ni][r] + bv_);
        *(f16x4*)&dst[((size_t)((b * 8 + h) * 64 + d)) * 4096 + tt] = ov;
      }
    }
  }
}

// ---------------- flash attention v4: occupancy via KV-tile halving --------
// Per-MFMA ratios IDENTICAL to the verified R4 kernel (128 queries/block,
// 32 q/wave); only the KV tile shrinks 128->64 keys. LDS 36864 B -> 4
// blocks/CU (4 waves/SIMD) to fill the dependency gaps the counters show
// (no pipe >42%, traffic L2-resident). 64 j-iters, 1 barrier each.
// XCD swizzle (R6), PV at K=32 via permlane32_swap + bit2<->3 V swizzle (R4),
// lsum on VALU (R1), setprio around MFMA clusters.
__global__ __launch_bounds__(256, 4)
void attn_kernel(const _Float16* __restrict__ Q, const _Float16* __restrict__ K,
                 const _Float16* __restrict__ V, _Float16* __restrict__ O) {
  __shared__ __align__(16) _Float16 Ks[2][64][72];
  __shared__ __align__(16) _Float16 Vt[2][64][72];

  const int t = threadIdx.x;
  const int lane = t & 63, wave = t >> 6;
  const int quad = lane >> 4, col = lane & 15;
  // XCD swizzle: id%8 = XCD (round-robin dispatch); give each XCD 2 whole bh
  const int id = blockIdx.y * 32 + blockIdx.x;
  const int xcd = id & 7, slot = id >> 3;
  const int bh = xcd * 2 + (slot >> 5);
  const int q0 = (slot & 31) * 128;
  const _Float16* Qb = Q + (size_t)bh * 4096 * 64;
  const _Float16* Kbh = K + (size_t)bh * 4096 * 64;
  const _Float16* Vg = V + (size_t)bh * 64 * 4096;   // [d][t]

  // staging coords (64x64 tiles, 256 threads x 2 f16x8 each)
  const int sr = (t * 8) >> 6, sc = (t * 8) & 63;    // K rows: sr, sr+32
  const int vrow = t >> 3, vcol = (t & 7) * 8;       // V^T rows: vrow, vrow+32
  const int vc0 = swz23(vcol);                       // sigma(vcol)
  const int vc1 = swz23(vcol + 4);                   // sigma(vcol+4)

  // Q as B-fragment: B[n=query=mt*16+col][k=d=ks*32+quad*8+j]
  f16x8 qf[2][2];
#pragma unroll
  for (int mt = 0; mt < 2; mt++)
#pragma unroll
    for (int ks = 0; ks < 2; ks++)
      qf[mt][ks] = *(const f16x8*)&Qb[(size_t)(q0 + wave * 32 + mt * 16 + col) * 64 +
                                      ks * 32 + quad * 8];

  const f32x4 fz = {0.f, 0.f, 0.f, 0.f};

  f16x8 kreg[2], vreg[2];
  // prologue: load + stage tile 0
#pragma unroll
  for (int i = 0; i < 2; i++)
    kreg[i] = *(const f16x8*)&Kbh[(size_t)(sr + 32 * i) * 64 + sc];
#pragma unroll
  for (int it = 0; it < 2; it++)
    vreg[it] = *(const f16x8*)&Vg[(size_t)(it * 32 + vrow) * 4096 + vcol];
#pragma unroll
  for (int i = 0; i < 2; i++)
    *(f16x8*)&Ks[0][sr + 32 * i][sc] = kreg[i];
#pragma unroll
  for (int it = 0; it < 2; it++) {
    f16x4 lo, hi;
#pragma unroll
    for (int u = 0; u < 4; u++) { lo[u] = vreg[it][u]; hi[u] = vreg[it][u + 4]; }
    *(f16x4*)&Vt[0][it * 32 + vrow][vc0] = lo;
    *(f16x4*)&Vt[0][it * 32 + vrow][vc1] = hi;
  }
  __syncthreads();

  // o_acc[mt][dt][r] = O^T[d=dt*16+quad*4+r][query=mt*16+col]
  f32x4 o_acc[2][4] = {};
  float lsum[2] = {0.f, 0.f};

  for (int j = 0; j < 64; j++) {
    const int buf = j & 1;
    // prefetch tile j+1 into registers (L2-resident after XCD swizzle)
    if (j + 1 < 64) {
      const _Float16* Kb = Kbh + (size_t)(j + 1) * 64 * 64;
#pragma unroll
      for (int i = 0; i < 2; i++)
        kreg[i] = *(const f16x8*)&Kb[(size_t)(sr + 32 * i) * 64 + sc];
#pragma unroll
      for (int it = 0; it < 2; it++)
        vreg[it] = *(const f16x8*)&Vg[(size_t)(it * 32 + vrow) * 4096 +
                                      (j + 1) * 64 + vcol];
    }

    // S^T[key][query]: s[mt][nt][r] = S[q=mt*16+col][key=nt*16+quad*4+r]
    f32x4 s[2][4];
    __builtin_amdgcn_s_setprio(1);
#pragma unroll
    for (int nt = 0; nt < 4; nt++) {
      f16x8 kf = *(const f16x8*)&Ks[buf][nt * 16 + col][quad * 8];
#pragma unroll
      for (int mt = 0; mt < 2; mt++)
        s[mt][nt] = __builtin_amdgcn_mfma_f32_16x16x32_f16(kf, qf[mt][0], fz, 0, 0, 0);
    }
#pragma unroll
    for (int nt = 0; nt < 4; nt++) {
      f16x8 kf = *(const f16x8*)&Ks[buf][nt * 16 + col][32 + quad * 8];
#pragma unroll
      for (int mt = 0; mt < 2; mt++)
        s[mt][nt] = __builtin_amdgcn_mfma_f32_16x16x32_f16(kf, qf[mt][1], s[mt][nt], 0, 0, 0);
    }
    __builtin_amdgcn_s_setprio(0);

    // P = exp2(S^T): bare v_exp_f32 + packed f32->f16; l-accum on VALU pipe
    f16x4 pf[2][4];
#pragma unroll
    for (int mt = 0; mt < 2; mt++) {
#pragma unroll
      for (int nt = 0; nt < 4; nt++) {
        float p0 = fast_exp2(s[mt][nt][0]);
        float p1 = fast_exp2(s[mt][nt][1]);
        float p2 = fast_exp2(s[mt][nt][2]);
        float p3 = fast_exp2(s[mt][nt][3]);
        lsum[mt] += (p0 + p1) + (p2 + p3);
        union { f16x4 v4; f16x2 v2[2]; } u;
        u.v2[0] = pk_cvt(p0, p1);
        u.v2[1] = pk_cvt(p2, p3);
        pf[mt][nt] = u.v4;
      }
    }

    // O^T += V^T P^T at K=32: build 8-keys/lane P fragments via permlane32_swap
    __builtin_amdgcn_s_setprio(1);
#pragma unroll
    for (int u = 0; u < 2; u++) {
      f16x8 p8[2];
#pragma unroll
      for (int mt = 0; mt < 2; mt++) {
        union { f16x4 v; int d[2]; } X, Y;
        X.v = pf[mt][2 * u]; Y.v = pf[mt][2 * u + 1];
        int x0 = X.d[0], y0 = Y.d[0], x1 = X.d[1], y1 = Y.d[1];
        qswap32(x0, y0);   // x0 = low halves (j0,1), y0 = high halves (j4,5)
        qswap32(x1, y1);   // x1 = (j2,3),           y1 = (j6,7)
        union { int d[4]; f16x8 v; } P;
        P.d[0] = x0; P.d[1] = x1; P.d[2] = y0; P.d[3] = y1;
        p8[mt] = P.v;
      }
#pragma unroll
      for (int dt = 0; dt < 4; dt++) {
        f16x8 vf = *(const f16x8*)&Vt[buf][dt * 16 + col][u * 32 + quad * 8];
#pragma unroll
        for (int mt = 0; mt < 2; mt++)
          o_acc[mt][dt] = __builtin_amdgcn_mfma_f32_16x16x32_f16(vf, p8[mt], o_acc[mt][dt], 0, 0, 0);
      }
    }
    __builtin_amdgcn_s_setprio(0);

    // write prefetched tile into the other buffer; single barrier per iter
    if (j + 1 < 64) {
      const int nb = buf ^ 1;
#pragma unroll
      for (int i = 0; i < 2; i++)
        *(f16x8*)&Ks[nb][sr + 32 * i][sc] = kreg[i];
#pragma unroll
      for (int it = 0; it < 2; it++) {
        f16x4 lo, hi;
#pragma unroll
        for (int u = 0; u < 4; u++) { lo[u] = vreg[it][u]; hi[u] = vreg[it][u + 4]; }
        *(f16x4*)&Vt[nb][it * 32 + vrow][vc0] = lo;
        *(f16x4*)&Vt[nb][it * 32 + vrow][vc1] = hi;
      }
      __syncthreads();
    }
  }

  // epilogue: complete l across quads (lanes col, col+16, col+32, col+48),
  // then O /= l, write [b][t][h*64+d] fp16 (row-major 8192x512)
  const int b = bh >> 3, h = bh & 7;
#pragma unroll
  for (int mt = 0; mt < 2; mt++) {
    float l = lsum[mt];
    l += __shfl_xor(l, 16, 64);
    l += __shfl_xor(l, 32, 64);
    int row = q0 + wave * 32 + mt * 16 + col;
    float inv = 1.0f / l;
#pragma unroll
    for (int dt = 0; dt < 4; dt++) {
      f16x4 ov;
#pragma unroll
      for (int r = 0; r < 4; r++) ov[r] = (_Float16)(o_acc[mt][dt][r] * inv);
      *(f16x4*)&O[((size_t)(b * 4096 + row)) * 512 + h * 64 + dt * 16 + quad * 4] = ov;
    }
  }
}

// ---------------- output projection: out = ao @ Wo^T + bo -> fp32 ----------
__global__ __launch_bounds__(256, 2)
void out_gemm(const _Float16* __restrict__ X, const _Float16* __restrict__ Wo,
              const float* __restrict__ bias, float* __restrict__ out) {
  __shared__ __align__(16) _Float16 As[128][72];
  __shared__ __align__(16) _Float16 Bs[128][72];
  const int t = threadIdx.x;
  const int lane = t & 63, wave = t >> 6;
  const int quad = lane >> 4, col = lane & 15;
  const int wm = (wave & 1) * 64, wn = (wave >> 1) * 64;
  const int m0 = blockIdx.x * 128, n0 = blockIdx.y * 128;

  f32x4 acc[4][4] = {};

  for (int k0 = 0; k0 < 512; k0 += 64) {
    __syncthreads();
#pragma unroll
    for (int i = 0; i < 4; i++) {
      int flat = i * 2048 + t * 8;
      int r = flat >> 6, c = flat & 63;
      *(f16x8*)&As[r][c] = *(const f16x8*)&X[(size_t)(m0 + r) * 512 + k0 + c];
      *(f16x8*)&Bs[r][c] = *(const f16x8*)&Wo[(size_t)(n0 + r) * 512 + k0 + c];
    }
    __syncthreads();
#pragma unroll
    for (int ks = 0; ks < 2; ks++) {
      f16x8 a[4], b[4];
#pragma unroll
      for (int i = 0; i < 4; i++) {
        a[i] = *(const f16x8*)&As[wm + i * 16 + col][ks * 32 + quad * 8];
        b[i] = *(const f16x8*)&Bs[wn + i * 16 + col][ks * 32 + quad * 8];
      }
#pragma unroll
      for (int mi = 0; mi < 4; mi++)
#pragma unroll
        for (int ni = 0; ni < 4; ni++)
          acc[mi][ni] = __builtin_amdgcn_mfma_f32_16x16x32_f16(a[mi], b[ni], acc[mi][ni], 0, 0, 0);
    }
  }

#pragma unroll
  for (int ni = 0; ni < 4; ni++) {
    int n = n0 + wn + ni * 16 + col;
    float bv_ = bias[n];
#pragma unroll
    for (int mi = 0; mi < 4; mi++) {
#pragma unroll
      for (int r = 0; r < 4; r++) {
        int m = m0 + wm + mi * 16 + quad * 4 + r;
        out[(size_t)m * 512 + n] = acc[mi][ni][r] + bv_;
      }
    }
  }
}

extern "C" void kernel_launch(void* const* d_in, const int* in_sizes, int n_in,
                              void* d_out, int out_size, void* d_ws, size_t ws_size,
                              hipStream_t stream) {
  const float* x  = (const float*)d_in[0];
  const float* Wq = (const float*)d_in[1];
  const float* bq = (const float*)d_in[2];
  const float* Wk = (const float*)d_in[3];
  const float* bk = (const float*)d_in[4];
  const float* Wv = (const float*)d_in[5];
  const float* bv = (const float*)d_in[6];
  const float* Wo = (const float*)d_in[7];
  const float* bo = (const float*)d_in[8];

  char* ws = (char*)d_ws;
  _Float16* xf  = (_Float16*)(ws);                 //  8 MiB: x as f16 (dead after qkv)
  _Float16* wf  = (_Float16*)(ws + (8u << 20));    //  2 MiB: Wq,Wk,Wv,Wo f16
  _Float16* qkv = (_Float16*)(ws + (10u << 20));   // 24 MiB: Q,K [bh][t][d]; V [bh][d][t]
  _Float16* ao  = (_Float16*)(ws);                 //  8 MiB: attn out (reuses xf)

  cvt_all<<<2560, 256, 0, stream>>>(x, Wq, Wk, Wv, Wo, xf, wf);

  qkv_gemm<<<dim3(64, 4, 3), 256, 0, stream>>>(xf, wf, bq, bk, bv, qkv);

  attn_kernel<<<dim3(32, 16), 256, 0, stream>>>(qkv, qkv + 4194304,
                                                qkv + 2 * 4194304, ao);

  out_gemm<<<dim3(64, 4), 256, 0, stream>>>(ao, wf + 3 * 262144, bo,
                                            (float*)d_out);
}

// Round 8
// 196.426 us; speedup vs baseline: 1.0466x; 1.0158x over previous
//
#include <hip/hip_runtime.h>

typedef _Float16 f16x8 __attribute__((ext_vector_type(8)));
typedef _Float16 f16x4 __attribute__((ext_vector_type(4)));
typedef _Float16 f16x2 __attribute__((ext_vector_type(2)));
typedef __fp16 hf16x2 __attribute__((ext_vector_type(2)));
typedef float f32x4 __attribute__((ext_vector_type(4)));

__device__ __forceinline__ float fast_exp2(float x) {
#if __has_builtin(__builtin_amdgcn_exp2f)
  return __builtin_amdgcn_exp2f(x);
#else
  return exp2f(x);
#endif
}

__device__ __forceinline__ f16x2 pk_cvt(float a, float b) {
#if __has_builtin(__builtin_amdgcn_cvt_pkrtz)
  union { hf16x2 h; f16x2 f; } u;
  u.h = __builtin_amdgcn_cvt_pkrtz(a, b);
  return u.f;
#else
  f16x2 r; r[0] = (_Float16)a; r[1] = (_Float16)b; return r;
#endif
}

// v_permlane32_swap_b32: x <- {x.lanes[0:31], y.lanes[0:31]},
//                        y <- {x.lanes[32:63], y.lanes[32:63]}
__device__ __forceinline__ void qswap32(int& x, int& y) {
  asm("v_permlane32_swap_b32 %0, %1" : "+v"(x), "+v"(y));
}

// key-index involution: swap bits 2 and 3 (sigma == pi, self-inverse)
__device__ __forceinline__ int swz23(int c) {
  return (c & ~12) | ((c & 4) << 1) | ((c & 8) >> 1);
}

// ---------------- fused f32 -> f16 convert prepass ----------------
__global__ void cvt_all(const float* __restrict__ x,
                        const float* __restrict__ Wq, const float* __restrict__ Wk,
                        const float* __restrict__ Wv, const float* __restrict__ Wo,
                        _Float16* __restrict__ xf, _Float16* __restrict__ wf) {
  int g = blockIdx.x * blockDim.x + threadIdx.x;
  const float* src;
  _Float16* dst;
  if (g < 524288) {
    src = x + (size_t)g * 8;
    dst = xf + (size_t)g * 8;
  } else {
    int g2 = g - 524288;
    int z = g2 >> 15, off = g2 & 32767;
    const float* W = (z == 0) ? Wq : (z == 1) ? Wk : (z == 2) ? Wv : Wo;
    src = W + (size_t)off * 8;
    dst = wf + (size_t)z * 262144 + (size_t)off * 8;
  }
  f32x4 a = *(const f32x4*)src;
  f32x4 b = *(const f32x4*)(src + 4);
  f16x8 o;
  o[0] = (_Float16)a[0]; o[1] = (_Float16)a[1];
  o[2] = (_Float16)a[2]; o[3] = (_Float16)a[3];
  o[4] = (_Float16)b[0]; o[5] = (_Float16)b[1];
  o[6] = (_Float16)b[2]; o[7] = (_Float16)b[3];
  *(f16x8*)dst = o;
}

// ---------------- fused QKV projection: y = x @ W^T + b ----------------
// Q,K (z=0,1): SWAPPED-operand MFMA (feature in row slot, token in col) ->
// f16x4 stores of 4 consecutive d per token. Branch hoisted OUT of the K-loop.
// V (z=2): original order, written TRANSPOSED [bh][d][t].
__global__ __launch_bounds__(256, 2)
void qkv_gemm(const _Float16* __restrict__ X, const _Float16* __restrict__ Wf,
              const float* __restrict__ bq, const float* __restrict__ bk,
              const float* __restrict__ bv, _Float16* __restrict__ dst3) {
  __shared__ __align__(16) _Float16 As[128][72];
  __shared__ __align__(16) _Float16 Bs[128][72];
  const int z = blockIdx.z;
  const _Float16* Wz = Wf + (size_t)z * 262144;
  const float* bias = (z == 0) ? bq : (z == 1 ? bk : bv);
  _Float16* dst = dst3 + (size_t)z * 4194304;
  const float scale = (z == 0) ? 0.18033688011112042f : 1.0f;

  const int t = threadIdx.x;
  const int lane = t & 63, wave = t >> 6;
  const int quad = lane >> 4, col = lane & 15;
  const int wm = (wave & 1) * 64, wn = (wave >> 1) * 64;
  const int m0 = blockIdx.x * 128, n0 = blockIdx.y * 128;

  f32x4 acc[4][4] = {};

  if (z != 2) {
    for (int k0 = 0; k0 < 512; k0 += 64) {
      __syncthreads();
#pragma unroll
      for (int i = 0; i < 4; i++) {
        int flat = i * 2048 + t * 8;
        int r = flat >> 6, c = flat & 63;
        *(f16x8*)&As[r][c] = *(const f16x8*)&X[(size_t)(m0 + r) * 512 + k0 + c];
        *(f16x8*)&Bs[r][c] = *(const f16x8*)&Wz[(size_t)(n0 + r) * 512 + k0 + c];
      }
      __syncthreads();
#pragma unroll
      for (int ks = 0; ks < 2; ks++) {
        f16x8 a[4], b[4];
#pragma unroll
        for (int i = 0; i < 4; i++) {
          a[i] = *(const f16x8*)&As[wm + i * 16 + col][ks * 32 + quad * 8];
          b[i] = *(const f16x8*)&Bs[wn + i * 16 + col][ks * 32 + quad * 8];
        }
#pragma unroll
        for (int mi = 0; mi < 4; mi++)
#pragma unroll
          for (int ni = 0; ni < 4; ni++)
            acc[mi][ni] = __builtin_amdgcn_mfma_f32_16x16x32_f16(b[ni], a[mi], acc[mi][ni], 0, 0, 0);
      }
    }
    // Q,K: [bh][t][d], f16x4 of 4 consecutive d per token
#pragma unroll
    for (int ni = 0; ni < 4; ni++) {
      int nb = n0 + wn + ni * 16 + quad * 4;   // 4 consecutive features
      int h = nb >> 6, d0 = nb & 63;
      f32x4 bb = *(const f32x4*)&bias[nb];
#pragma unroll
      for (int mi = 0; mi < 4; mi++) {
        int m = m0 + wm + mi * 16 + col;
        int b = m >> 12, tt = m & 4095;
        f16x4 ov;
#pragma unroll
        for (int r = 0; r < 4; r++)
          ov[r] = (_Float16)((acc[mi][ni][r] + bb[r]) * scale);
        *(f16x4*)&dst[((size_t)(b * 8 + h) * 4096 + tt) * 64 + d0] = ov;
      }
    }
  } else {
    for (int k0 = 0; k0 < 512; k0 += 64) {
      __syncthreads();
#pragma unroll
      for (int i = 0; i < 4; i++) {
        int flat = i * 2048 + t * 8;
        int r = flat >> 6, c = flat & 63;
        *(f16x8*)&As[r][c] = *(const f16x8*)&X[(size_t)(m0 + r) * 512 + k0 + c];
        *(f16x8*)&Bs[r][c] = *(const f16x8*)&Wz[(size_t)(n0 + r) * 512 + k0 + c];
      }
      __syncthreads();
#pragma unroll
      for (int ks = 0; ks < 2; ks++) {
        f16x8 a[4], b[4];
#pragma unroll
        for (int i = 0; i < 4; i++) {
          a[i] = *(const f16x8*)&As[wm + i * 16 + col][ks * 32 + quad * 8];
          b[i] = *(const f16x8*)&Bs[wn + i * 16 + col][ks * 32 + quad * 8];
        }
#pragma unroll
        for (int mi = 0; mi < 4; mi++)
#pragma unroll
          for (int ni = 0; ni < 4; ni++)
            acc[mi][ni] = __builtin_amdgcn_mfma_f32_16x16x32_f16(a[mi], b[ni], acc[mi][ni], 0, 0, 0);
      }
    }
    // V: [bh][d][t] layout, vectorized f16x4 along t
#pragma unroll
    for (int ni = 0; ni < 4; ni++) {
      int n = n0 + wn + ni * 16 + col;
      float bv_ = bias[n];
      int h = n >> 6, d = n & 63;
#pragma unroll
      for (int mi = 0; mi < 4; mi++) {
        int m = m0 + wm + mi * 16 + quad * 4;
        int b = m >> 12, tt = m & 4095;
        f16x4 ov;
#pragma unroll
        for (int r = 0; r < 4; r++) ov[r] = (_Float16)(acc[mi][ni][r] + bv_);
        *(f16x4*)&dst[((size_t)((b * 8 + h) * 64 + d)) * 4096 + tt] = ov;
      }
    }
  }
}

// ---------------- flash attention v5: 2-deep pipeline, triple-buffer -------
// Per tile T: STAGE(T+1) -> barrier -> QKT(T+1)->S_next -> LOADT(T+2) ->
// EXPPV(T, S_cur). QKT(T+1) is register-independent of exp(T): the wave
// issues exp VALU under the QK MFMAs, breaking the serial QK->exp->PV chain
// WITHIN each wave. Triple-buffered LDS gives ONE barrier/iter (STAGE(buf b)
// at tile T vs last reader EXPPV(T-2) separated by the T-1 barrier).
// Period-6 unroll (3 bufs x 2 s-states), all indices static.
// 64-key tiles, XCD swizzle, PV at K=32 via permlane32_swap + bit2<->3
// V swizzle, lsum on VALU, setprio around MFMA clusters.
__global__ __launch_bounds__(256, 2)
void attn_kernel(const _Float16* __restrict__ Q, const _Float16* __restrict__ K,
                 const _Float16* __restrict__ V, _Float16* __restrict__ O) {
  __shared__ __align__(16) _Float16 Ks[3][64][72];
  __shared__ __align__(16) _Float16 Vt[3][64][72];

  const int t = threadIdx.x;
  const int lane = t & 63, wave = t >> 6;
  const int quad = lane >> 4, col = lane & 15;
  // XCD swizzle: id%8 = XCD (round-robin dispatch); give each XCD 2 whole bh
  const int id = blockIdx.y * 32 + blockIdx.x;
  const int xcd = id & 7, slot = id >> 3;
  const int bh = xcd * 2 + (slot >> 5);
  const int q0 = (slot & 31) * 128;
  const _Float16* Qb = Q + (size_t)bh * 4096 * 64;
  const _Float16* Kbh = K + (size_t)bh * 4096 * 64;
  const _Float16* Vg = V + (size_t)bh * 64 * 4096;   // [d][t]

  // staging coords (64x64 tiles, 256 threads x 2 f16x8 each)
  const int sr = (t * 8) >> 6, sc = (t * 8) & 63;    // K rows: sr, sr+32
  const int vrow = t >> 3, vcol = (t & 7) * 8;       // V^T rows: vrow, vrow+32
  const int vc0 = swz23(vcol);                       // sigma(vcol)
  const int vc1 = swz23(vcol + 4);                   // sigma(vcol+4)

  // Q as B-fragment: B[n=query=mt*16+col][k=d=ks*32+quad*8+j]
  f16x8 qf[2][2];
#pragma unroll
  for (int mt = 0; mt < 2; mt++)
#pragma unroll
    for (int ks = 0; ks < 2; ks++)
      qf[mt][ks] = *(const f16x8*)&Qb[(size_t)(q0 + wave * 32 + mt * 16 + col) * 64 +
                                      ks * 32 + quad * 8];

  const f32x4 fz = {0.f, 0.f, 0.f, 0.f};

  f16x8 kreg[2], vreg[2];
  f32x4 sA[2][4], sB[2][4];
  f32x4 o_acc[2][4] = {};
  float lsum[2] = {0.f, 0.f};

#define LOADT(J)                                                              \
  {                                                                           \
    const _Float16* Kb_ = Kbh + (size_t)(J) * 64 * 64;                        \
    _Pragma("unroll") for (int i = 0; i < 2; i++)                             \
      kreg[i] = *(const f16x8*)&Kb_[(size_t)(sr + 32 * i) * 64 + sc];         \
    _Pragma("unroll") for (int it = 0; it < 2; it++)                          \
      vreg[it] = *(const f16x8*)&Vg[(size_t)(it * 32 + vrow) * 4096 +         \
                                    (size_t)(J) * 64 + vcol];                 \
  }

#define STAGE(NB)                                                             \
  {                                                                           \
    _Pragma("unroll") for (int i = 0; i < 2; i++)                             \
      *(f16x8*)&Ks[(NB)][sr + 32 * i][sc] = kreg[i];                          \
    _Pragma("unroll") for (int it = 0; it < 2; it++) {                        \
      f16x4 lo, hi;                                                           \
      _Pragma("unroll") for (int u = 0; u < 4; u++) {                         \
        lo[u] = vreg[it][u]; hi[u] = vreg[it][u + 4];                         \
      }                                                                       \
      *(f16x4*)&Vt[(NB)][it * 32 + vrow][vc0] = lo;                           \
      *(f16x4*)&Vt[(NB)][it * 32 + vrow][vc1] = hi;                           \
    }                                                                         \
  }

#define QKT(NB, S)                                                            \
  {                                                                           \
    __builtin_amdgcn_s_setprio(1);                                            \
    _Pragma("unroll") for (int nt = 0; nt < 4; nt++) {                        \
      f16x8 kf = *(const f16x8*)&Ks[(NB)][nt * 16 + col][quad * 8];           \
      _Pragma("unroll") for (int mt = 0; mt < 2; mt++)                        \
        S[mt][nt] = __builtin_amdgcn_mfma_f32_16x16x32_f16(kf, qf[mt][0],     \
                                                           fz, 0, 0, 0);      \
    }                                                                         \
    _Pragma("unroll") for (int nt = 0; nt < 4; nt++) {                        \
      f16x8 kf = *(const f16x8*)&Ks[(NB)][nt * 16 + col][32 + quad * 8];      \
      _Pragma("unroll") for (int mt = 0; mt < 2; mt++)                        \
        S[mt][nt] = __builtin_amdgcn_mfma_f32_16x16x32_f16(kf, qf[mt][1],     \
                                                           S[mt][nt], 0, 0, 0); \
    }                                                                         \
    __builtin_amdgcn_s_setprio(0);                                            \
  }

#define EXPPV(CB, S)                                                          \
  {                                                                           \
    f16x4 pf[2][4];                                                           \
    _Pragma("unroll") for (int mt = 0; mt < 2; mt++)                          \
      _Pragma("unroll") for (int nt = 0; nt < 4; nt++) {                      \
        float p0 = fast_exp2(S[mt][nt][0]);                                   \
        float p1 = fast_exp2(S[mt][nt][1]);                                   \
        float p2 = fast_exp2(S[mt][nt][2]);                                   \
        float p3 = fast_exp2(S[mt][nt][3]);                                   \
        lsum[mt] += (p0 + p1) + (p2 + p3);                                    \
        union { f16x4 v4; f16x2 v2[2]; } u_;                                  \
        u_.v2[0] = pk_cvt(p0, p1);                                            \
        u_.v2[1] = pk_cvt(p2, p3);                                            \
        pf[mt][nt] = u_.v4;                                                   \
      }                                                                       \
    __builtin_amdgcn_s_setprio(1);                                            \
    _Pragma("unroll") for (int u = 0; u < 2; u++) {                           \
      f16x8 p8[2];                                                            \
      _Pragma("unroll") for (int mt = 0; mt < 2; mt++) {                      \
        union { f16x4 v; int d[2]; } X_, Y_;                                  \
        X_.v = pf[mt][2 * u]; Y_.v = pf[mt][2 * u + 1];                       \
        int x0 = X_.d[0], y0 = Y_.d[0], x1 = X_.d[1], y1 = Y_.d[1];           \
        qswap32(x0, y0);                                                      \
        qswap32(x1, y1);                                                      \
        union { int d[4]; f16x8 v; } P_;                                      \
        P_.d[0] = x0; P_.d[1] = x1; P_.d[2] = y0; P_.d[3] = y1;               \
        p8[mt] = P_.v;                                                        \
      }                                                                       \
      _Pragma("unroll") for (int dt = 0; dt < 4; dt++) {                      \
        f16x8 vf = *(const f16x8*)&Vt[(CB)][dt * 16 + col][u * 32 + quad * 8]; \
        _Pragma("unroll") for (int mt = 0; mt < 2; mt++)                      \
          o_acc[mt][dt] = __builtin_amdgcn_mfma_f32_16x16x32_f16(             \
              vf, p8[mt], o_acc[mt][dt], 0, 0, 0);                            \
      }                                                                       \
    }                                                                         \
    __builtin_amdgcn_s_setprio(0);                                            \
  }

// tile T: stage T+1, barrier, QKT(T+1)->PROD, prefetch T+2, EXPPV(T, CONS)
#define PBODY(CUR, NXT, CONS, PROD, JLOAD, DOLOAD)                            \
  {                                                                           \
    STAGE(NXT);                                                               \
    __syncthreads();                                                          \
    QKT(NXT, PROD);                                                           \
    if (DOLOAD) LOADT(JLOAD);                                                 \
    EXPPV(CUR, CONS);                                                         \
  }

  // prologue: tile0 -> buf0, prefetch tile1, scores(tile0) -> sA
  LOADT(0);
  STAGE(0);
  LOADT(1);
  __syncthreads();
  QKT(0, sA);

  for (int jt = 0; jt < 60; jt += 6) {
    PBODY(0, 1, sA, sB, jt + 2, true);
    PBODY(1, 2, sB, sA, jt + 3, true);
    PBODY(2, 0, sA, sB, jt + 4, true);
    PBODY(0, 1, sB, sA, jt + 5, true);
    PBODY(1, 2, sA, sB, jt + 6, true);
    PBODY(2, 0, sB, sA, jt + 7, true);
  }
  PBODY(0, 1, sA, sB, 62, true);   // tile 60
  PBODY(1, 2, sB, sA, 63, true);   // tile 61
  PBODY(2, 0, sA, sB, 0, false);   // tile 62 (stages tile 63)
  EXPPV(0, sB);                    // tile 63

#undef LOADT
#undef STAGE
#undef QKT
#undef EXPPV
#undef PBODY

  // epilogue: complete l across quads (lanes col, col+16, col+32, col+48),
  // then O /= l, write [b][t][h*64+d] fp16 (row-major 8192x512)
  const int b = bh >> 3, h = bh & 7;
#pragma unroll
  for (int mt = 0; mt < 2; mt++) {
    float l = lsum[mt];
    l += __shfl_xor(l, 16, 64);
    l += __shfl_xor(l, 32, 64);
    int row = q0 + wave * 32 + mt * 16 + col;
    float inv = 1.0f / l;
#pragma unroll
    for (int dt = 0; dt < 4; dt++) {
      f16x4 ov;
#pragma unroll
      for (int r = 0; r < 4; r++) ov[r] = (_Float16)(o_acc[mt][dt][r] * inv);
      *(f16x4*)&O[((size_t)(b * 4096 + row)) * 512 + h * 64 + dt * 16 + quad * 4] = ov;
    }
  }
}

// ---------------- output projection: out = ao @ Wo^T + bo -> fp32 ----------
__global__ __launch_bounds__(256, 2)
void out_gemm(const _Float16* __restrict__ X, const _Float16* __restrict__ Wo,
              const float* __restrict__ bias, float* __restrict__ out) {
  __shared__ __align__(16) _Float16 As[128][72];
  __shared__ __align__(16) _Float16 Bs[128][72];
  const int t = threadIdx.x;
  const int lane = t & 63, wave = t >> 6;
  const int quad = lane >> 4, col = lane & 15;
  const int wm = (wave & 1) * 64, wn = (wave >> 1) * 64;
  const int m0 = blockIdx.x * 128, n0 = blockIdx.y * 128;

  f32x4 acc[4][4] = {};

  for (int k0 = 0; k0 < 512; k0 += 64) {
    __syncthreads();
#pragma unroll
    for (int i = 0; i < 4; i++) {
      int flat = i * 2048 + t * 8;
      int r = flat >> 6, c = flat & 63;
      *(f16x8*)&As[r][c] = *(const f16x8*)&X[(size_t)(m0 + r) * 512 + k0 + c];
      *(f16x8*)&Bs[r][c] = *(const f16x8*)&Wo[(size_t)(n0 + r) * 512 + k0 + c];
    }
    __syncthreads();
#pragma unroll
    for (int ks = 0; ks < 2; ks++) {
      f16x8 a[4], b[4];
#pragma unroll
      for (int i = 0; i < 4; i++) {
        a[i] = *(const f16x8*)&As[wm + i * 16 + col][ks * 32 + quad * 8];
        b[i] = *(const f16x8*)&Bs[wn + i * 16 + col][ks * 32 + quad * 8];
      }
#pragma unroll
      for (int mi = 0; mi < 4; mi++)
#pragma unroll
        for (int ni = 0; ni < 4; ni++)
          acc[mi][ni] = __builtin_amdgcn_mfma_f32_16x16x32_f16(a[mi], b[ni], acc[mi][ni], 0, 0, 0);
    }
  }

#pragma unroll
  for (int ni = 0; ni < 4; ni++) {
    int n = n0 + wn + ni * 16 + col;
    float bv_ = bias[n];
#pragma unroll
    for (int mi = 0; mi < 4; mi++) {
#pragma unroll
      for (int r = 0; r < 4; r++) {
        int m = m0 + wm + mi * 16 + quad * 4 + r;
        out[(size_t)m * 512 + n] = acc[mi][ni][r] + bv_;
      }
    }
  }
}

extern "C" void kernel_launch(void* const* d_in, const int* in_sizes, int n_in,
                              void* d_out, int out_size, void* d_ws, size_t ws_size,
                              hipStream_t stream) {
  const float* x  = (const float*)d_in[0];
  const float* Wq = (const float*)d_in[1];
  const float* bq = (const float*)d_in[2];
  const float* Wk = (const float*)d_in[3];
  const float* bk = (const float*)d_in[4];
  const float* Wv = (const float*)d_in[5];
  const float* bv = (const float*)d_in[6];
  const float* Wo = (const float*)d_in[7];
  const float* bo = (const float*)d_in[8];

  char* ws = (char*)d_ws;
  _Float16* xf  = (_Float16*)(ws);                 //  8 MiB: x as f16 (dead after qkv)
  _Float16* wf  = (_Float16*)(ws + (8u << 20));    //  2 MiB: Wq,Wk,Wv,Wo f16
  _Float16* qkv = (_Float16*)(ws + (10u << 20));   // 24 MiB: Q,K [bh][t][d]; V [bh][d][t]
  _Float16* ao  = (_Float16*)(ws);                 //  8 MiB: attn out (reuses xf)

  cvt_all<<<2560, 256, 0, stream>>>(x, Wq, Wk, Wv, Wo, xf, wf);

  qkv_gemm<<<dim3(64, 4, 3), 256, 0, stream>>>(xf, wf, bq, bk, bv, qkv);

  attn_kernel<<<dim3(32, 16), 256, 0, stream>>>(qkv, qkv + 4194304,
                                                qkv + 2 * 4194304, ao);

  out_gemm<<<dim3(64, 4), 256, 0, stream>>>(ao, wf + 3 * 262144, bo,
                                            (float*)d_out);
}

// Round 9
// 192.250 us; speedup vs baseline: 1.0693x; 1.0217x over previous
//
#include <hip/hip_runtime.h>

typedef _Float16 f16x8 __attribute__((ext_vector_type(8)));
typedef _Float16 f16x4 __attribute__((ext_vector_type(4)));
typedef _Float16 f16x2 __attribute__((ext_vector_type(2)));
typedef __fp16 hf16x2 __attribute__((ext_vector_type(2)));
typedef float f32x4 __attribute__((ext_vector_type(4)));

__device__ __forceinline__ float fast_exp2(float x) {
#if __has_builtin(__builtin_amdgcn_exp2f)
  return __builtin_amdgcn_exp2f(x);
#else
  return exp2f(x);
#endif
}

__device__ __forceinline__ f16x2 pk_cvt(float a, float b) {
#if __has_builtin(__builtin_amdgcn_cvt_pkrtz)
  union { hf16x2 h; f16x2 f; } u;
  u.h = __builtin_amdgcn_cvt_pkrtz(a, b);
  return u.f;
#else
  f16x2 r; r[0] = (_Float16)a; r[1] = (_Float16)b; return r;
#endif
}

// v_permlane32_swap_b32: x <- {x.lanes[0:31], y.lanes[0:31]},
//                        y <- {x.lanes[32:63], y.lanes[32:63]}
__device__ __forceinline__ void qswap32(int& x, int& y) {
  asm("v_permlane32_swap_b32 %0, %1" : "+v"(x), "+v"(y));
}

// key-index involution: swap bits 2 and 3 (sigma == pi, self-inverse)
__device__ __forceinline__ int swz23(int c) {
  return (c & ~12) | ((c & 4) << 1) | ((c & 8) >> 1);
}

// ---------------- fused f32 -> f16 convert prepass ----------------
__global__ void cvt_all(const float* __restrict__ x,
                        const float* __restrict__ Wq, const float* __restrict__ Wk,
                        const float* __restrict__ Wv, const float* __restrict__ Wo,
                        _Float16* __restrict__ xf, _Float16* __restrict__ wf) {
  int g = blockIdx.x * blockDim.x + threadIdx.x;
  const float* src;
  _Float16* dst;
  if (g < 524288) {
    src = x + (size_t)g * 8;
    dst = xf + (size_t)g * 8;
  } else {
    int g2 = g - 524288;
    int z = g2 >> 15, off = g2 & 32767;
    const float* W = (z == 0) ? Wq : (z == 1) ? Wk : (z == 2) ? Wv : Wo;
    src = W + (size_t)off * 8;
    dst = wf + (size_t)z * 262144 + (size_t)off * 8;
  }
  f32x4 a = *(const f32x4*)src;
  f32x4 b = *(const f32x4*)(src + 4);
  f16x8 o;
  o[0] = (_Float16)a[0]; o[1] = (_Float16)a[1];
  o[2] = (_Float16)a[2]; o[3] = (_Float16)a[3];
  o[4] = (_Float16)b[0]; o[5] = (_Float16)b[1];
  o[6] = (_Float16)b[2]; o[7] = (_Float16)b[3];
  *(f16x8*)dst = o;
}

// ---------------- fused QKV projection: y = x @ W^T + b ----------------
// v2: reg-prefetch double-buffered K-loop (attn's verified 1-barrier/step
// schedule: STAGE(next); LOAD(next+2); barrier; COMPUTE(next)) hides global
// latency that the old 2-barrier loop exposed every k-step. XCD swizzle:
// each XCD owns an 8-m-tile stripe across all (n,z) -> X panel (1MB/XCD)
// read once from HBM, reused 12x from its L2.
// Q,K (z!=2): swapped-operand MFMA -> f16x4 stores of 4 consecutive d.
// V (z==2): normal order, written TRANSPOSED [bh][d][t].
__global__ __launch_bounds__(256, 2)
void qkv_gemm(const _Float16* __restrict__ X, const _Float16* __restrict__ Wf,
              const float* __restrict__ bq, const float* __restrict__ bk,
              const float* __restrict__ bv, _Float16* __restrict__ dst3) {
  __shared__ __align__(16) _Float16 As[2][128][72];
  __shared__ __align__(16) _Float16 Bs[2][128][72];
  // XCD swizzle (bijective, 768 = 8 xcd x 96)
  const int id = (blockIdx.z * 4 + blockIdx.y) * 64 + blockIdx.x;
  const int xcd = id & 7, s = id >> 3;          // s in [0,96)
  const int m0 = (xcd * 8 + (s & 7)) * 128;     // m-tile in [0,64)
  const int yz = s >> 3;                        // [0,12)
  const int n0 = (yz & 3) * 128;
  const int z = yz >> 2;
  const _Float16* Wz = Wf + (size_t)z * 262144;
  const float* bias = (z == 0) ? bq : (z == 1 ? bk : bv);
  _Float16* dst = dst3 + (size_t)z * 4194304;
  const float scale = (z == 0) ? 0.18033688011112042f : 1.0f;

  const int t = threadIdx.x;
  const int lane = t & 63, wave = t >> 6;
  const int quad = lane >> 4, col = lane & 15;
  const int wm = (wave & 1) * 64, wn = (wave >> 1) * 64;
  const int sr = (t * 8) >> 6, sc = (t * 8) & 63;   // staging row/col (per i: +32)

  f32x4 acc[4][4] = {};
  f16x8 areg[4], breg[4];

#define GLOAD(K0)                                                             \
  {                                                                           \
    _Pragma("unroll") for (int i = 0; i < 4; i++) {                           \
      areg[i] = *(const f16x8*)&X[(size_t)(m0 + sr + 32 * i) * 512 + (K0) + sc]; \
      breg[i] = *(const f16x8*)&Wz[(size_t)(n0 + sr + 32 * i) * 512 + (K0) + sc]; \
    }                                                                         \
  }

#define GSTAGE(B)                                                             \
  {                                                                           \
    _Pragma("unroll") for (int i = 0; i < 4; i++) {                           \
      *(f16x8*)&As[(B)][sr + 32 * i][sc] = areg[i];                           \
      *(f16x8*)&Bs[(B)][sr + 32 * i][sc] = breg[i];                           \
    }                                                                         \
  }

#define GCOMP_QK(B)                                                           \
  {                                                                           \
    _Pragma("unroll") for (int ks = 0; ks < 2; ks++) {                        \
      f16x8 a[4], b[4];                                                       \
      _Pragma("unroll") for (int i = 0; i < 4; i++) {                         \
        a[i] = *(const f16x8*)&As[(B)][wm + i * 16 + col][ks * 32 + quad * 8]; \
        b[i] = *(const f16x8*)&Bs[(B)][wn + i * 16 + col][ks * 32 + quad * 8]; \
      }                                                                       \
      _Pragma("unroll") for (int mi = 0; mi < 4; mi++)                        \
        _Pragma("unroll") for (int ni = 0; ni < 4; ni++)                      \
          acc[mi][ni] = __builtin_amdgcn_mfma_f32_16x16x32_f16(               \
              b[ni], a[mi], acc[mi][ni], 0, 0, 0);                            \
    }                                                                         \
  }

#define GCOMP_V(B)                                                            \
  {                                                                           \
    _Pragma("unroll") for (int ks = 0; ks < 2; ks++) {                        \
      f16x8 a[4], b[4];                                                       \
      _Pragma("unroll") for (int i = 0; i < 4; i++) {                         \
        a[i] = *(const f16x8*)&As[(B)][wm + i * 16 + col][ks * 32 + quad * 8]; \
        b[i] = *(const f16x8*)&Bs[(B)][wn + i * 16 + col][ks * 32 + quad * 8]; \
      }                                                                       \
      _Pragma("unroll") for (int mi = 0; mi < 4; mi++)                        \
        _Pragma("unroll") for (int ni = 0; ni < 4; ni++)                      \
          acc[mi][ni] = __builtin_amdgcn_mfma_f32_16x16x32_f16(               \
              a[mi], b[ni], acc[mi][ni], 0, 0, 0);                            \
    }                                                                         \
  }

  if (z != 2) {
    GLOAD(0); GSTAGE(0); GLOAD(64);
    __syncthreads();
    GCOMP_QK(0);
    GSTAGE(1); GLOAD(128); __syncthreads(); GCOMP_QK(1);
    GSTAGE(0); GLOAD(192); __syncthreads(); GCOMP_QK(0);
    GSTAGE(1); GLOAD(256); __syncthreads(); GCOMP_QK(1);
    GSTAGE(0); GLOAD(320); __syncthreads(); GCOMP_QK(0);
    GSTAGE(1); GLOAD(384); __syncthreads(); GCOMP_QK(1);
    GSTAGE(0); GLOAD(448); __syncthreads(); GCOMP_QK(0);
    GSTAGE(1); __syncthreads(); GCOMP_QK(1);
    // Q,K: [bh][t][d], f16x4 of 4 consecutive d per token
#pragma unroll
    for (int ni = 0; ni < 4; ni++) {
      int nb = n0 + wn + ni * 16 + quad * 4;   // 4 consecutive features
      int h = nb >> 6, d0 = nb & 63;
      f32x4 bb = *(const f32x4*)&bias[nb];
#pragma unroll
      for (int mi = 0; mi < 4; mi++) {
        int m = m0 + wm + mi * 16 + col;
        int b = m >> 12, tt = m & 4095;
        f16x4 ov;
#pragma unroll
        for (int r = 0; r < 4; r++)
          ov[r] = (_Float16)((acc[mi][ni][r] + bb[r]) * scale);
        *(f16x4*)&dst[((size_t)(b * 8 + h) * 4096 + tt) * 64 + d0] = ov;
      }
    }
  } else {
    GLOAD(0); GSTAGE(0); GLOAD(64);
    __syncthreads();
    GCOMP_V(0);
    GSTAGE(1); GLOAD(128); __syncthreads(); GCOMP_V(1);
    GSTAGE(0); GLOAD(192); __syncthreads(); GCOMP_V(0);
    GSTAGE(1); GLOAD(256); __syncthreads(); GCOMP_V(1);
    GSTAGE(0); GLOAD(320); __syncthreads(); GCOMP_V(0);
    GSTAGE(1); GLOAD(384); __syncthreads(); GCOMP_V(1);
    GSTAGE(0); GLOAD(448); __syncthreads(); GCOMP_V(0);
    GSTAGE(1); __syncthreads(); GCOMP_V(1);
    // V: [bh][d][t] layout, vectorized f16x4 along t
#pragma unroll
    for (int ni = 0; ni < 4; ni++) {
      int n = n0 + wn + ni * 16 + col;
      float bv_ = bias[n];
      int h = n >> 6, d = n & 63;
#pragma unroll
      for (int mi = 0; mi < 4; mi++) {
        int m = m0 + wm + mi * 16 + quad * 4;
        int b = m >> 12, tt = m & 4095;
        f16x4 ov;
#pragma unroll
        for (int r = 0; r < 4; r++) ov[r] = (_Float16)(acc[mi][ni][r] + bv_);
        *(f16x4*)&dst[((size_t)((b * 8 + h) * 64 + d)) * 4096 + tt] = ov;
      }
    }
  }
#undef GLOAD
#undef GSTAGE
#undef GCOMP_QK
#undef GCOMP_V
}

// ---------------- flash attention (R6-verified, 92.2 us) -------------------
// 128-key KV tiles, 32 q/wave, reg-prefetch dbuf, XCD swizzle (2 bh/XCD),
// PV at K=32 via permlane32_swap + bit2<->3 V swizzle, lsum on VALU,
// setprio around MFMA clusters.
__global__ __launch_bounds__(256, 2)
void attn_kernel(const _Float16* __restrict__ Q, const _Float16* __restrict__ K,
                 const _Float16* __restrict__ V, _Float16* __restrict__ O) {
  __shared__ __align__(16) _Float16 Ks[2][128][72];
  __shared__ __align__(16) _Float16 Vt[2][64][136]; // pitch 136: 16B-aligned rows

  const int t = threadIdx.x;
  const int lane = t & 63, wave = t >> 6;
  const int quad = lane >> 4, col = lane & 15;
  // XCD swizzle: id%8 = XCD (round-robin dispatch); give each XCD 2 whole bh
  const int id = blockIdx.y * 32 + blockIdx.x;
  const int xcd = id & 7, slot = id >> 3;
  const int bh = xcd * 2 + (slot >> 5);
  const int q0 = (slot & 31) * 128;
  const _Float16* Qb = Q + (size_t)bh * 4096 * 64;
  const _Float16* Kbh = K + (size_t)bh * 4096 * 64;
  const _Float16* Vg = V + (size_t)bh * 64 * 4096;   // [d][t]

  // staging coords
  const int sr = (t * 8) >> 6, sc = (t * 8) & 63;    // K rows: r = sr + 32*i
  const int vrow = t >> 4, vcol = (t & 15) * 8;      // V^T rows: d = vrow + 16*it
  const int vc0 = swz23(vcol);                       // sigma(vcol)
  const int vc1 = swz23(vcol + 4);                   // sigma(vcol+4)

  // Q as B-fragment: B[n=query=mt*16+col][k=d=ks*32+quad*8+j]
  f16x8 qf[2][2];
#pragma unroll
  for (int mt = 0; mt < 2; mt++)
#pragma unroll
    for (int ks = 0; ks < 2; ks++)
      qf[mt][ks] = *(const f16x8*)&Qb[(size_t)(q0 + wave * 32 + mt * 16 + col) * 64 +
                                      ks * 32 + quad * 8];

  const f32x4 fz = {0.f, 0.f, 0.f, 0.f};

  f16x8 kreg[4], vreg[4];
  // prologue: load tile 0
#pragma unroll
  for (int i = 0; i < 4; i++)
    kreg[i] = *(const f16x8*)&Kbh[(size_t)(sr + 32 * i) * 64 + sc];
#pragma unroll
  for (int it = 0; it < 4; it++)
    vreg[it] = *(const f16x8*)&Vg[(size_t)(it * 16 + vrow) * 4096 + vcol];
#pragma unroll
  for (int i = 0; i < 4; i++)
    *(f16x8*)&Ks[0][sr + 32 * i][sc] = kreg[i];
#pragma unroll
  for (int it = 0; it < 4; it++) {
    f16x4 lo, hi;
#pragma unroll
    for (int u = 0; u < 4; u++) { lo[u] = vreg[it][u]; hi[u] = vreg[it][u + 4]; }
    *(f16x4*)&Vt[0][it * 16 + vrow][vc0] = lo;
    *(f16x4*)&Vt[0][it * 16 + vrow][vc1] = hi;
  }
  __syncthreads();

  // o_acc[mt][dt][r] = O^T[d=dt*16+quad*4+r][query=mt*16+col]
  f32x4 o_acc[2][4] = {};
  // per-lane partial row-sum of P for query=col, keys {nt*16+quad*4+r, all nt,j}
  float lsum[2] = {0.f, 0.f};

  for (int j = 0; j < 32; j++) {
    const int buf = j & 1;
    // prefetch tile j+1 into registers (latency hidden behind compute)
    if (j + 1 < 32) {
      const _Float16* Kb = Kbh + (size_t)(j + 1) * 128 * 64;
#pragma unroll
      for (int i = 0; i < 4; i++)
        kreg[i] = *(const f16x8*)&Kb[(size_t)(sr + 32 * i) * 64 + sc];
#pragma unroll
      for (int it = 0; it < 4; it++)
        vreg[it] = *(const f16x8*)&Vg[(size_t)(it * 16 + vrow) * 4096 +
                                      (j + 1) * 128 + vcol];
    }

    // S^T[key][query]: s[mt][nt][r] = S[q=mt*16+col][key=nt*16+quad*4+r]
    f32x4 s[2][8];
    __builtin_amdgcn_s_setprio(1);
#pragma unroll
    for (int nt = 0; nt < 8; nt++) {
      f16x8 kf = *(const f16x8*)&Ks[buf][nt * 16 + col][quad * 8];
#pragma unroll
      for (int mt = 0; mt < 2; mt++)
        s[mt][nt] = __builtin_amdgcn_mfma_f32_16x16x32_f16(kf, qf[mt][0], fz, 0, 0, 0);
    }
#pragma unroll
    for (int nt = 0; nt < 8; nt++) {
      f16x8 kf = *(const f16x8*)&Ks[buf][nt * 16 + col][32 + quad * 8];
#pragma unroll
      for (int mt = 0; mt < 2; mt++)
        s[mt][nt] = __builtin_amdgcn_mfma_f32_16x16x32_f16(kf, qf[mt][1], s[mt][nt], 0, 0, 0);
    }
    __builtin_amdgcn_s_setprio(0);

    // P = exp2(S^T): bare v_exp_f32 + packed f32->f16; l-accum on VALU pipe
    f16x4 pf[2][8];
#pragma unroll
    for (int mt = 0; mt < 2; mt++) {
#pragma unroll
      for (int nt = 0; nt < 8; nt++) {
        float p0 = fast_exp2(s[mt][nt][0]);
        float p1 = fast_exp2(s[mt][nt][1]);
        float p2 = fast_exp2(s[mt][nt][2]);
        float p3 = fast_exp2(s[mt][nt][3]);
        lsum[mt] += (p0 + p1) + (p2 + p3);
        union { f16x4 v4; f16x2 v2[2]; } u;
        u.v2[0] = pk_cvt(p0, p1);
        u.v2[1] = pk_cvt(p2, p3);
        pf[mt][nt] = u.v4;
      }
    }

    // O^T += V^T P^T at K=32: build 8-keys/lane P fragments via permlane32_swap
    __builtin_amdgcn_s_setprio(1);
#pragma unroll
    for (int u = 0; u < 4; u++) {
      f16x8 p8[2];
#pragma unroll
      for (int mt = 0; mt < 2; mt++) {
        union { f16x4 v; int d[2]; } X, Y;
        X.v = pf[mt][2 * u]; Y.v = pf[mt][2 * u + 1];
        int x0 = X.d[0], y0 = Y.d[0], x1 = X.d[1], y1 = Y.d[1];
        qswap32(x0, y0);   // x0 = low halves (j0,1), y0 = high halves (j4,5)
        qswap32(x1, y1);   // x1 = (j2,3),           y1 = (j6,7)
        union { int d[4]; f16x8 v; } P;
        P.d[0] = x0; P.d[1] = x1; P.d[2] = y0; P.d[3] = y1;
        p8[mt] = P.v;
      }
#pragma unroll
      for (int dt = 0; dt < 4; dt++) {
        f16x8 vf = *(const f16x8*)&Vt[buf][dt * 16 + col][u * 32 + quad * 8];
#pragma unroll
        for (int mt = 0; mt < 2; mt++)
          o_acc[mt][dt] = __builtin_amdgcn_mfma_f32_16x16x32_f16(vf, p8[mt], o_acc[mt][dt], 0, 0, 0);
      }
    }
    __builtin_amdgcn_s_setprio(0);

    // write prefetched tile into the other buffer; single barrier per iter
    if (j + 1 < 32) {
      const int nb = buf ^ 1;
#pragma unroll
      for (int i = 0; i < 4; i++)
        *(f16x8*)&Ks[nb][sr + 32 * i][sc] = kreg[i];
#pragma unroll
      for (int it = 0; it < 4; it++) {
        f16x4 lo, hi;
#pragma unroll
        for (int u = 0; u < 4; u++) { lo[u] = vreg[it][u]; hi[u] = vreg[it][u + 4]; }
        *(f16x4*)&Vt[nb][it * 16 + vrow][vc0] = lo;
        *(f16x4*)&Vt[nb][it * 16 + vrow][vc1] = hi;
      }
      __syncthreads();
    }
  }

  // epilogue: complete l across quads (lanes col, col+16, col+32, col+48),
  // then O /= l, write [b][t][h*64+d] fp16 (row-major 8192x512)
  const int b = bh >> 3, h = bh & 7;
#pragma unroll
  for (int mt = 0; mt < 2; mt++) {
    float l = lsum[mt];
    l += __shfl_xor(l, 16, 64);
    l += __shfl_xor(l, 32, 64);
    int row = q0 + wave * 32 + mt * 16 + col;
    float inv = 1.0f / l;
#pragma unroll
    for (int dt = 0; dt < 4; dt++) {
      f16x4 ov;
#pragma unroll
      for (int r = 0; r < 4; r++) ov[r] = (_Float16)(o_acc[mt][dt][r] * inv);
      *(f16x4*)&O[((size_t)(b * 4096 + row)) * 512 + h * 64 + dt * 16 + quad * 4] = ov;
    }
  }
}

// ---------------- output projection: out = ao @ Wo^T + bo -> fp32 ----------
// v2: reg-prefetch double-buffer (1 barrier/step), XCD swizzle, swapped-operand
// MFMA -> f32x4 stores of 4 consecutive n per token.
__global__ __launch_bounds__(256, 2)
void out_gemm(const _Float16* __restrict__ X, const _Float16* __restrict__ Wo,
              const float* __restrict__ bias, float* __restrict__ out) {
  __shared__ __align__(16) _Float16 As[2][128][72];
  __shared__ __align__(16) _Float16 Bs[2][128][72];
  // XCD swizzle (bijective, 256 = 8 xcd x 32)
  const int id = blockIdx.y * 64 + blockIdx.x;
  const int xcd = id & 7, s = id >> 3;          // s in [0,32)
  const int m0 = (xcd * 8 + (s & 7)) * 128;
  const int n0 = (s >> 3) * 128;

  const int t = threadIdx.x;
  const int lane = t & 63, wave = t >> 6;
  const int quad = lane >> 4, col = lane & 15;
  const int wm = (wave & 1) * 64, wn = (wave >> 1) * 64;
  const int sr = (t * 8) >> 6, sc = (t * 8) & 63;

  f32x4 acc[4][4] = {};
  f16x8 areg[4], breg[4];

#define OLOAD(K0)                                                             \
  {                                                                           \
    _Pragma("unroll") for (int i = 0; i < 4; i++) {                           \
      areg[i] = *(const f16x8*)&X[(size_t)(m0 + sr + 32 * i) * 512 + (K0) + sc]; \
      breg[i] = *(const f16x8*)&Wo[(size_t)(n0 + sr + 32 * i) * 512 + (K0) + sc]; \
    }                                                                         \
  }

#define OSTAGE(B)                                                             \
  {                                                                           \
    _Pragma("unroll") for (int i = 0; i < 4; i++) {                           \
      *(f16x8*)&As[(B)][sr + 32 * i][sc] = areg[i];                           \
      *(f16x8*)&Bs[(B)][sr + 32 * i][sc] = breg[i];                           \
    }                                                                         \
  }

#define OCOMP(B)                                                              \
  {                                                                           \
    _Pragma("unroll") for (int ks = 0; ks < 2; ks++) {                        \
      f16x8 a[4], b[4];                                                       \
      _Pragma("unroll") for (int i = 0; i < 4; i++) {                         \
        a[i] = *(const f16x8*)&As[(B)][wm + i * 16 + col][ks * 32 + quad * 8]; \
        b[i] = *(const f16x8*)&Bs[(B)][wn + i * 16 + col][ks * 32 + quad * 8]; \
      }                                                                       \
      _Pragma("unroll") for (int mi = 0; mi < 4; mi++)                        \
        _Pragma("unroll") for (int ni = 0; ni < 4; ni++)                      \
          acc[mi][ni] = __builtin_amdgcn_mfma_f32_16x16x32_f16(               \
              b[ni], a[mi], acc[mi][ni], 0, 0, 0);                            \
    }                                                                         \
  }

  OLOAD(0); OSTAGE(0); OLOAD(64);
  __syncthreads();
  OCOMP(0);
  OSTAGE(1); OLOAD(128); __syncthreads(); OCOMP(1);
  OSTAGE(0); OLOAD(192); __syncthreads(); OCOMP(0);
  OSTAGE(1); OLOAD(256); __syncthreads(); OCOMP(1);
  OSTAGE(0); OLOAD(320); __syncthreads(); OCOMP(0);
  OSTAGE(1); OLOAD(384); __syncthreads(); OCOMP(1);
  OSTAGE(0); OLOAD(448); __syncthreads(); OCOMP(0);
  OSTAGE(1); __syncthreads(); OCOMP(1);
#undef OLOAD
#undef OSTAGE
#undef OCOMP

  // swapped layout: acc[mi][ni][r] = out[m0+wm+mi*16+col][n0+wn+ni*16+quad*4+r]
#pragma unroll
  for (int ni = 0; ni < 4; ni++) {
    int nb = n0 + wn + ni * 16 + quad * 4;
    f32x4 bb = *(const f32x4*)&bias[nb];
#pragma unroll
    for (int mi = 0; mi < 4; mi++) {
      int m = m0 + wm + mi * 16 + col;
      f32x4 ov;
#pragma unroll
      for (int r = 0; r < 4; r++) ov[r] = acc[mi][ni][r] + bb[r];
      *(f32x4*)&out[(size_t)m * 512 + nb] = ov;
    }
  }
}

extern "C" void kernel_launch(void* const* d_in, const int* in_sizes, int n_in,
                              void* d_out, int out_size, void* d_ws, size_t ws_size,
                              hipStream_t stream) {
  const float* x  = (const float*)d_in[0];
  const float* Wq = (const float*)d_in[1];
  const float* bq = (const float*)d_in[2];
  const float* Wk = (const float*)d_in[3];
  const float* bk = (const float*)d_in[4];
  const float* Wv = (const float*)d_in[5];
  const float* bv = (const float*)d_in[6];
  const float* Wo = (const float*)d_in[7];
  const float* bo = (const float*)d_in[8];

  char* ws = (char*)d_ws;
  _Float16* xf  = (_Float16*)(ws);                 //  8 MiB: x as f16 (dead after qkv)
  _Float16* wf  = (_Float16*)(ws + (8u << 20));    //  2 MiB: Wq,Wk,Wv,Wo f16
  _Float16* qkv = (_Float16*)(ws + (10u << 20));   // 24 MiB: Q,K [bh][t][d]; V [bh][d][t]
  _Float16* ao  = (_Float16*)(ws);                 //  8 MiB: attn out (reuses xf)

  cvt_all<<<2560, 256, 0, stream>>>(x, Wq, Wk, Wv, Wo, xf, wf);

  qkv_gemm<<<dim3(64, 4, 3), 256, 0, stream>>>(xf, wf, bq, bk, bv, qkv);

  attn_kernel<<<dim3(32, 16), 256, 0, stream>>>(qkv, qkv + 4194304,
                                                qkv + 2 * 4194304, ao);

  out_gemm<<<dim3(64, 4), 256, 0, stream>>>(ao, Wo == nullptr ? nullptr : wf + 3 * 262144, bo,
                                            (float*)d_out);
}